// Round 14
// baseline (477.425 us; speedup 1.0000x reference)
//
#include <hip/hip_runtime.h>
#include <cstdint>
#include <cstddef>

#define N_NODES 20000
#define N_EDGES 400000
#define NBLK 79  // ceil(20000/256)
#define MPAD 20128  // N_NODES rounded up to 128-row tiles

typedef __attribute__((ext_vector_type(8))) short bf16x8;
typedef __attribute__((ext_vector_type(4))) float f32x4;

// ---------- bf16 helpers (manual, bit-exact) ----------
__device__ __forceinline__ float bf2f(unsigned short u) {
    return __uint_as_float(((unsigned int)u) << 16);
}
__device__ __forceinline__ unsigned short f2bf(float f) {
    unsigned int x = __float_as_uint(f);
    unsigned int lsb = (x >> 16) & 1u;
    x += 0x7fffu + lsb;  // round-to-nearest-even
    return (unsigned short)(x >> 16);
}

// ---------- flag-aware loads for harness float tensors (bf16 or fp32) ----------
__device__ __forceinline__ float ldF(const void* p, size_t i, bool bf) {
    return bf ? bf2f(((const unsigned short*)p)[i]) : ((const float*)p)[i];
}

// ---------- async global->LDS 16B copy ----------
__device__ __forceinline__ void gl2lds16(const unsigned short* g, unsigned short* l) {
    __builtin_amdgcn_global_load_lds(
        (const __attribute__((address_space(1))) void*)g,
        (__attribute__((address_space(3))) void*)l, 16, 0, 0);
}

// ---------- dtype + int64 detection (one wave, lane-parallel) ----------
__global__ void k_detect(const unsigned int* __restrict__ xw, const int* __restrict__ raw,
                         int* __restrict__ flag) {
    int lane = threadIdx.x;
    int cnt = 0, nz = 0;
    for (int i = lane; i < 256; i += 64) {
        unsigned short lo = (unsigned short)(xw[i] & 0xffffu);
        int e = (lo >> 7) & 0xff;
        if (e >= 110 && e <= 135) cnt++;
    }
    for (int i = 2 * lane + 1; i < 512; i += 128)
        if (raw[i] != 0) nz++;
#pragma unroll
    for (int off = 32; off > 0; off >>= 1) {
        cnt += __shfl_down(cnt, off);
        nz  += __shfl_down(nz, off);
    }
    if (lane == 0) {
        flag[0] = (cnt >= 128) ? 1 : 0;  // 1 = float tensors are bf16
        flag[1] = (nz == 0) ? 1 : 0;     // 1 = edge_index is raw int64
    }
}

// ---------- canonicalize edge_index + degree + counts (fused) ----------
__global__ void k_canon_deg(const int* __restrict__ raw, const void* __restrict__ ew,
                            const int* __restrict__ flagp,
                            int* __restrict__ src32, int* __restrict__ dst32,
                            float* __restrict__ deg, int* __restrict__ counts) {
    bool bf = (flagp[0] != 0);
    int is64 = flagp[1];
    int e = blockIdx.x * blockDim.x + threadIdx.x;
    if (e >= N_EDGES) return;
    int s, d;
    if (is64) { s = raw[2 * e]; d = raw[2 * (N_EDGES + e)]; }
    else      { s = raw[e];     d = raw[N_EDGES + e]; }
    src32[e] = s;
    dst32[e] = d;
    atomicAdd(&deg[d], ldF(ew, e, bf));
    atomicAdd(&counts[d], 1);
}

// ---------- pass 1: per-block count sums + fused dinv/selfnorm ----------
__global__ __launch_bounds__(256) void k_part(const int* __restrict__ counts,
                                              const float* __restrict__ deg,
                                              float* __restrict__ dinv,
                                              float* __restrict__ selfnorm,
                                              int* __restrict__ bsum) {
    __shared__ int s[256];
    int t = threadIdx.x;
    int i = blockIdx.x * 256 + t;
    int c = (i < N_NODES) ? counts[i] : 0;
    if (i < N_NODES) {
        float d = deg[i] + 1.0f;
        float r = rsqrtf(d);
        dinv[i] = r;
        selfnorm[i] = r * r;
    }
    s[t] = c;
    __syncthreads();
    for (int off = 128; off > 0; off >>= 1) {
        if (t < off) s[t] += s[t + off];
        __syncthreads();
    }
    if (t == 0) bsum[blockIdx.x] = s[0];
}

// ---------- pass 2: exclusive scan of 79 block sums (1 tiny block) ----------
__global__ void k_scanb(const int* __restrict__ bsum, int* __restrict__ bofs,
                        int* __restrict__ rowptr) {
    __shared__ int s[128];
    int t = threadIdx.x;
    int v = (t < NBLK) ? bsum[t] : 0;
    s[t] = v;
    __syncthreads();
    for (int off = 1; off < 128; off <<= 1) {
        int u = (t >= off) ? s[t - off] : 0;
        __syncthreads();
        s[t] += u;
        __syncthreads();
    }
    if (t < NBLK) bofs[t] = s[t] - v;  // exclusive
    if (t == NBLK - 1) rowptr[N_NODES] = s[t];
}

// ---------- pass 3: intra-block scan + block offset -> rowptr ----------
__global__ __launch_bounds__(256) void k_row(const int* __restrict__ counts,
                                             const int* __restrict__ bofs,
                                             int* __restrict__ rowptr) {
    __shared__ int s[256];
    int t = threadIdx.x;
    int b = blockIdx.x;
    int i = b * 256 + t;
    int c = (i < N_NODES) ? counts[i] : 0;
    s[t] = c;
    __syncthreads();
    for (int off = 1; off < 256; off <<= 1) {
        int u = (t >= off) ? s[t - off] : 0;
        __syncthreads();
        s[t] += u;
        __syncthreads();
    }
    if (i < N_NODES) rowptr[i] = bofs[b] + s[t] - c;
}

// ---------- scatter edges into CSR-by-dst with per-edge norm ----------
__global__ void k_csr(const int* __restrict__ src, const int* __restrict__ dst,
                      const void* __restrict__ ew, const int* __restrict__ flagp,
                      const float* __restrict__ dinv, const int* __restrict__ rowptr,
                      int* __restrict__ fill, int* __restrict__ csr_src,
                      float* __restrict__ csr_norm) {
    bool bf = (*flagp != 0);
    int e = blockIdx.x * blockDim.x + threadIdx.x;
    if (e >= N_EDGES) return;
    int s = src[e], d = dst[e];
    int p = rowptr[d] + atomicAdd(&fill[d], 1);
    csr_src[p] = s;
    csr_norm[p] = dinv[s] * ldF(ew, e, bf) * dinv[d];
}

// ---------- merged prep: pack weights | cast biases+W5 -> fp32 ----------
// blocks [0,448): pack_all (gidx < 114688); [448,457): biases + W5
__global__ __launch_bounds__(256) void k_prep(const void* __restrict__ W1,
                                              const void* __restrict__ W2,
                                              const void* __restrict__ W3,
                                              const void* __restrict__ W4,
                                              const void* __restrict__ b1,
                                              const void* __restrict__ b2,
                                              const void* __restrict__ b3,
                                              const void* __restrict__ b4,
                                              const void* __restrict__ W5,
                                              const int* __restrict__ flagp,
                                              unsigned short* __restrict__ Wp,
                                              float* __restrict__ biasf) {
    bool bf = (*flagp != 0);
    int b = blockIdx.x;
    int t = threadIdx.x;
    if (b < 448) {
        int gidx = b * 256 + t;
        if (gidx >= 114688) return;
        const void* W;
        int idx = gidx, N, nbl;
        if (gidx < 32768)      { W = W1; N = 512; nbl = 5; }
        else if (gidx < 65536) { W = W2; N = 512; nbl = 5; idx -= 32768; }
        else if (gidx < 98304) { W = W3; N = 512; nbl = 5; idx -= 65536; }
        else                   { W = W4; N = 256; nbl = 4; idx -= 98304; }
        int lane = idx & 63;
        int blk = idx >> 6;
        int nb = blk & ((1 << nbl) - 1);
        int kb = blk >> nbl;
        int n = (nb << 4) + (lane & 15);
        int kbase = (kb << 5) + ((lane >> 4) << 3);
        unsigned short o[8];
#pragma unroll
        for (int j = 0; j < 8; ++j)
            o[j] = f2bf(ldF(W, (size_t)(kbase + j) * N + n, bf));
        *(uint4*)(&Wp[(size_t)gidx * 8]) = *(const uint4*)o;
    } else {
        int i = (b - 448) * 256 + t;
        if (i >= 2304) return;
        if (i < 2048) {
            int L = i >> 9, r = i & 511;
            if (L == 3 && r >= 256) return;
            const void* bb = (L == 0) ? b1 : (L == 1) ? b2 : (L == 2) ? b3 : b4;
            biasf[i] = ldF(bb, r, bf);
        } else {
            biasf[i] = ldF(W5, i - 2048, bf);  // fp32 W5 at biasf[2048..2303]
        }
    }
}

// ---------- MFMA bf16 GEMM, 128x128 tile, BK=64: C = A * Wp(packed) ----------
// raw=0: A is our bf16 P table. raw=1: A is the harness x tensor (dtype per
// flagp[0]); fp32 path converts to bf16 during LDS staging (fuses the x-cast).
__global__ __launch_bounds__(256) void k_gemm_mfma(const void* __restrict__ A,
                                                   const unsigned short* __restrict__ Bp,
                                                   unsigned short* __restrict__ C,
                                                   int M, int K, int N, int raw,
                                                   const int* __restrict__ flagp) {
    const int AP = 72;  // A-tile row stride (64 + 8 pad) shorts -> 2-way-max banks
    __shared__ __align__(16) unsigned short As[128 * AP];  // 18432 B
    __shared__ __align__(16) unsigned short Bs[2 * 8 * 512];  // 16384 B
    bool xbf = raw ? (flagp[0] != 0) : true;
    int tid = threadIdx.x;
    int lane = tid & 63;
    int wave = tid >> 6;
    int wr = wave >> 1, wc = wave & 1;
    int row0 = blockIdx.x * 128;
    int col0 = blockIdx.y * 128;
    int nbt = N >> 4;
    int q = lane >> 4;
    int mm = lane & 15;

    f32x4 acc[4][4] = {};

    for (int kb2 = 0; kb2 < (K >> 6); ++kb2) {
        // B: two packed kb-regions (k 0-31 and 32-63 of this BK), 8 KB each
        const unsigned short* breg0 = Bp + (((size_t)(2 * kb2) * nbt + (col0 >> 4)) << 9);
        const unsigned short* breg1 = Bp + (((size_t)(2 * kb2 + 1) * nbt + (col0 >> 4)) << 9);
        gl2lds16(breg0 + (size_t)tid * 8, &Bs[(size_t)tid * 8]);
        gl2lds16(breg0 + (size_t)(tid + 256) * 8, &Bs[(size_t)(tid + 256) * 8]);
        gl2lds16(breg1 + (size_t)tid * 8, &Bs[4096 + (size_t)tid * 8]);
        gl2lds16(breg1 + (size_t)(tid + 256) * 8, &Bs[4096 + (size_t)(tid + 256) * 8]);
        // A tile: 128 rows x 64 k (16KB), 1024 x 16B chunks, 4 per thread
#pragma unroll
        for (int i = 0; i < 4; ++i) {
            int c = tid + i * 256;
            int row = c >> 3, kq = c & 7;
            int grow = row0 + row;
            size_t eoff = (size_t)grow * K + (kb2 << 6) + (kq << 3);
            uint4 v = make_uint4(0u, 0u, 0u, 0u);
            if (grow < M) {
                if (xbf) {
                    v = *(const uint4*)(&((const unsigned short*)A)[eoff]);
                } else {
                    const float* xf = (const float*)A + eoff;
                    float4 a = *(const float4*)xf;
                    float4 bb = *(const float4*)(xf + 4);
                    v.x = (unsigned int)f2bf(a.x)  | ((unsigned int)f2bf(a.y)  << 16);
                    v.y = (unsigned int)f2bf(a.z)  | ((unsigned int)f2bf(a.w)  << 16);
                    v.z = (unsigned int)f2bf(bb.x) | ((unsigned int)f2bf(bb.y) << 16);
                    v.w = (unsigned int)f2bf(bb.z) | ((unsigned int)f2bf(bb.w) << 16);
                }
            }
            *(uint4*)(&As[row * AP + (kq << 3)]) = v;
        }
        __syncthreads();
#pragma unroll
        for (int kk = 0; kk < 2; ++kk) {
            bf16x8 af[4], bfr[4];
#pragma unroll
            for (int mb = 0; mb < 4; ++mb)
                af[mb] = *(const bf16x8*)(&As[(wr * 64 + mb * 16 + mm) * AP + kk * 32 + q * 8]);
#pragma unroll
            for (int nb = 0; nb < 4; ++nb)
                bfr[nb] = *(const bf16x8*)(&Bs[kk * 4096 + ((wc * 4 + nb) * 64 + lane) * 8]);
#pragma unroll
            for (int mb = 0; mb < 4; ++mb)
#pragma unroll
                for (int nb = 0; nb < 4; ++nb)
                    acc[mb][nb] = __builtin_amdgcn_mfma_f32_16x16x32_bf16(
                        af[mb], bfr[nb], acc[mb][nb], 0, 0, 0);
        }
        __syncthreads();
    }
#pragma unroll
    for (int mb = 0; mb < 4; ++mb) {
#pragma unroll
        for (int r = 0; r < 4; ++r) {
            int grow = row0 + wr * 64 + mb * 16 + q * 4 + r;
            if (grow < M) {
#pragma unroll
                for (int nb = 0; nb < 4; ++nb) {
                    int gcol = col0 + wc * 64 + nb * 16 + mm;
                    C[(size_t)grow * N + gcol] = f2bf(acc[mb][nb][r]);
                }
            }
        }
    }
}

// ---------- row-load + fma helpers for the gather ----------
template <int W>
__device__ __forceinline__ void ldrow(const unsigned short* h, size_t row, int F, int lane,
                                      unsigned int* u) {
    const unsigned int* p = (const unsigned int*)(h + row * F) + lane * W;
    if constexpr (W == 4) {
        uint4 v = *(const uint4*)p; u[0] = v.x; u[1] = v.y; u[2] = v.z; u[3] = v.w;
    } else {
        uint2 v = *(const uint2*)p; u[0] = v.x; u[1] = v.y;
    }
}
template <int W>
__device__ __forceinline__ void fmarow(const unsigned int* u, float w, float* acc) {
#pragma unroll
    for (int k = 0; k < W; ++k) {
        acc[2 * k]     = fmaf(bf2f((unsigned short)(u[k] & 0xffffu)), w, acc[2 * k]);
        acc[2 * k + 1] = fmaf(bf2f((unsigned short)(u[k] >> 16)),     w, acc[2 * k + 1]);
    }
}

// ---------- wave-per-node gather-aggregate, 4-edge unroll (F=512) ----------
__global__ __launch_bounds__(256) void k_agg_w(const unsigned short* __restrict__ h,
                                               const int* __restrict__ rowptr,
                                               const int* __restrict__ csr_src,
                                               const float* __restrict__ csr_norm,
                                               const float* __restrict__ selfnorm,
                                               const float* __restrict__ biasf,
                                               unsigned short* __restrict__ out) {
    constexpr int F = 512, FPL = 8, W = 4;
    int lane = threadIdx.x & 63;
    int wave = threadIdx.x >> 6;
    int node = blockIdx.x * 4 + wave;
    if (node >= N_NODES) return;
    int e0 = rowptr[node], e1 = rowptr[node + 1];
    float sn = selfnorm[node];

    float acc[FPL];
    {
        unsigned int u[W];
        ldrow<W>(h, (size_t)node, F, lane, u);
#pragma unroll
        for (int k = 0; k < W; ++k) {
            acc[2 * k]     = sn * bf2f((unsigned short)(u[k] & 0xffffu));
            acc[2 * k + 1] = sn * bf2f((unsigned short)(u[k] >> 16));
        }
    }
    int j = e0;
    for (; j + 3 < e1; j += 4) {
        int s0 = csr_src[j], s1 = csr_src[j + 1], s2 = csr_src[j + 2], s3 = csr_src[j + 3];
        float w0 = csr_norm[j], w1 = csr_norm[j + 1], w2 = csr_norm[j + 2], w3 = csr_norm[j + 3];
        unsigned int u0[W], u1[W], u2[W], u3[W];
        ldrow<W>(h, (size_t)s0, F, lane, u0);
        ldrow<W>(h, (size_t)s1, F, lane, u1);
        ldrow<W>(h, (size_t)s2, F, lane, u2);
        ldrow<W>(h, (size_t)s3, F, lane, u3);
        fmarow<W>(u0, w0, acc);
        fmarow<W>(u1, w1, acc);
        fmarow<W>(u2, w2, acc);
        fmarow<W>(u3, w3, acc);
    }
    for (; j < e1; ++j) {
        int s0 = csr_src[j];
        float w0 = csr_norm[j];
        unsigned int u0[W];
        ldrow<W>(h, (size_t)s0, F, lane, u0);
        fmarow<W>(u0, w0, acc);
    }
    {
        const float* bp = biasf + lane * FPL;
#pragma unroll
        for (int k = 0; k < FPL; ++k) acc[k] = fmaxf(acc[k] + bp[k], 0.f);
        unsigned int o[W];
#pragma unroll
        for (int k = 0; k < W; ++k)
            o[k] = (unsigned int)f2bf(acc[2 * k]) | ((unsigned int)f2bf(acc[2 * k + 1]) << 16);
        *(uint4*)((unsigned int*)(out + (size_t)node * F) + lane * W) =
            make_uint4(o[0], o[1], o[2], o[3]);
    }
}

// ---------- L4 agg fused with L5 GEMV: h5[node] = dot(relu(agg+b4), W5) ----------
__global__ __launch_bounds__(256) void k_agg_fuse(const unsigned short* __restrict__ h,
                                                  const int* __restrict__ rowptr,
                                                  const int* __restrict__ csr_src,
                                                  const float* __restrict__ csr_norm,
                                                  const float* __restrict__ selfnorm,
                                                  const float* __restrict__ biasf,
                                                  const float* __restrict__ w5f,
                                                  float* __restrict__ h5) {
    constexpr int F = 256, FPL = 4, W = 2;
    int lane = threadIdx.x & 63;
    int wave = threadIdx.x >> 6;
    int node = blockIdx.x * 4 + wave;
    if (node >= N_NODES) return;
    int e0 = rowptr[node], e1 = rowptr[node + 1];
    float sn = selfnorm[node];

    float acc[FPL];
    {
        unsigned int u[W];
        ldrow<W>(h, (size_t)node, F, lane, u);
#pragma unroll
        for (int k = 0; k < W; ++k) {
            acc[2 * k]     = sn * bf2f((unsigned short)(u[k] & 0xffffu));
            acc[2 * k + 1] = sn * bf2f((unsigned short)(u[k] >> 16));
        }
    }
    int j = e0;
    for (; j + 3 < e1; j += 4) {
        int s0 = csr_src[j], s1 = csr_src[j + 1], s2 = csr_src[j + 2], s3 = csr_src[j + 3];
        float w0 = csr_norm[j], w1 = csr_norm[j + 1], w2 = csr_norm[j + 2], w3 = csr_norm[j + 3];
        unsigned int u0[W], u1[W], u2[W], u3[W];
        ldrow<W>(h, (size_t)s0, F, lane, u0);
        ldrow<W>(h, (size_t)s1, F, lane, u1);
        ldrow<W>(h, (size_t)s2, F, lane, u2);
        ldrow<W>(h, (size_t)s3, F, lane, u3);
        fmarow<W>(u0, w0, acc);
        fmarow<W>(u1, w1, acc);
        fmarow<W>(u2, w2, acc);
        fmarow<W>(u3, w3, acc);
    }
    for (; j < e1; ++j) {
        int s0 = csr_src[j];
        float w0 = csr_norm[j];
        unsigned int u0[W];
        ldrow<W>(h, (size_t)s0, F, lane, u0);
        fmarow<W>(u0, w0, acc);
    }
    const float* bp = biasf + lane * FPL;
    const float* wp = w5f + lane * FPL;
    float partial = 0.f;
#pragma unroll
    for (int k = 0; k < FPL; ++k)
        partial += fmaxf(acc[k] + bp[k], 0.f) * wp[k];
#pragma unroll
    for (int off = 32; off > 0; off >>= 1)
        partial += __shfl_xor(partial, off);
    if (lane == 0) h5[node] = partial;
}

// ---------- final scalar aggregate, write output in harness dtype ----------
__global__ void k_final(const float* __restrict__ h5, const int* __restrict__ rowptr,
                        const int* __restrict__ csr_src, const float* __restrict__ csr_norm,
                        const float* __restrict__ selfnorm,
                        const void* __restrict__ b5, const int* __restrict__ flagp,
                        void* __restrict__ out) {
    bool bf = (*flagp != 0);
    int i = blockIdx.x * blockDim.x + threadIdx.x;
    if (i >= N_NODES) return;
    float acc = selfnorm[i] * h5[i];
    int e0 = rowptr[i], e1 = rowptr[i + 1];
    for (int j = e0; j < e1; ++j) acc += csr_norm[j] * h5[csr_src[j]];
    acc += ldF(b5, 0, bf);
    if (bf) ((unsigned short*)out)[i] = f2bf(acc);
    else    ((float*)out)[i] = acc;
}

extern "C" void kernel_launch(void* const* d_in, const int* in_sizes, int n_in,
                              void* d_out, int out_size, void* d_ws, size_t ws_size,
                              hipStream_t stream) {
    const void* x  = d_in[0];
    const int*  ei = (const int*)d_in[1];
    const void* ea = d_in[2];
    const void* W1 = d_in[3];
    const void* b1 = d_in[4];
    const void* W2 = d_in[5];
    const void* b2 = d_in[6];
    const void* W3 = d_in[7];
    const void* b3 = d_in[8];
    const void* W4 = d_in[9];
    const void* b4 = d_in[10];
    const void* W5 = d_in[11];
    const void* b5 = d_in[12];

    char* ws = (char*)d_ws;
    size_t off = 0;
    auto take = [&](size_t bytes) -> void* {
        off = (off + 255) & ~(size_t)255;
        void* p = ws + off;
        off += bytes;
        return p;
    };
    int*   flagp    = (int*)take(2 * sizeof(int));
    float* deg      = (float*)take(N_NODES * sizeof(float));
    int*   counts   = (int*)take(N_NODES * sizeof(int));
    int*   fill     = (int*)take(N_NODES * sizeof(int));
    size_t zspan    = (size_t)((char*)(fill + N_NODES) - (char*)deg);
    float* dinv     = (float*)take(N_NODES * sizeof(float));
    float* selfnorm = (float*)take(N_NODES * sizeof(float));
    float* h5       = (float*)take(N_NODES * sizeof(float));
    float* biasf    = (float*)take(2304 * sizeof(float));  // 4x512 biases + 256 W5
    int*   bsum     = (int*)take(128 * sizeof(int));
    int*   bofs     = (int*)take(128 * sizeof(int));
    int*   rowptr   = (int*)take((N_NODES + 1) * sizeof(int));
    int*   src32    = (int*)take(N_EDGES * sizeof(int));
    int*   dst32    = (int*)take(N_EDGES * sizeof(int));
    int*   csr_src  = (int*)take(N_EDGES * sizeof(int));
    float* csr_norm = (float*)take(N_EDGES * sizeof(float));
    unsigned short* Wp = (unsigned short*)take((size_t)114688 * 8 * sizeof(unsigned short));
    unsigned short* P  = (unsigned short*)take((size_t)MPAD * 512 * sizeof(unsigned short));
    unsigned short* H  = (unsigned short*)take((size_t)MPAD * 512 * sizeof(unsigned short));

    hipMemsetAsync(deg, 0, zspan, stream);

    const int EB = (N_EDGES + 255) / 256;
    const int NB = (N_NODES + 255) / 256;  // 79 == NBLK
    const int AGB = (N_NODES + 3) / 4;

    k_detect<<<1, 64, 0, stream>>>((const unsigned int*)x, ei, flagp);
    k_canon_deg<<<EB, 256, 0, stream>>>(ei, ea, flagp, src32, dst32, deg, counts);
    k_part<<<NB, 256, 0, stream>>>(counts, deg, dinv, selfnorm, bsum);
    k_scanb<<<1, 128, 0, stream>>>(bsum, bofs, rowptr);
    k_row<<<NB, 256, 0, stream>>>(counts, bofs, rowptr);
    k_csr<<<EB, 256, 0, stream>>>(src32, dst32, ea, flagp, dinv, rowptr, fill, csr_src, csr_norm);

    k_prep<<<457, 256, 0, stream>>>(W1, W2, W3, W4, b1, b2, b3, b4, W5, flagp, Wp, biasf);

    const int MB128 = (N_NODES + 127) / 128;  // 157

    // L1: GEMM reads x directly (fused cast), raw=1
    k_gemm_mfma<<<dim3(MB128, 4), 256, 0, stream>>>(x, Wp, H, N_NODES, 512, 512, 1, flagp);
    k_agg_w<<<AGB, 256, 0, stream>>>(H, rowptr, csr_src, csr_norm, selfnorm, biasf, P);
    k_gemm_mfma<<<dim3(MB128, 4), 256, 0, stream>>>(P, Wp + (size_t)32768 * 8, H,
                                                    N_NODES, 512, 512, 0, flagp);
    k_agg_w<<<AGB, 256, 0, stream>>>(H, rowptr, csr_src, csr_norm, selfnorm, biasf + 512, P);
    k_gemm_mfma<<<dim3(MB128, 4), 256, 0, stream>>>(P, Wp + (size_t)65536 * 8, H,
                                                    N_NODES, 512, 512, 0, flagp);
    k_agg_w<<<AGB, 256, 0, stream>>>(H, rowptr, csr_src, csr_norm, selfnorm, biasf + 1024, P);
    k_gemm_mfma<<<dim3(MB128, 2), 256, 0, stream>>>(P, Wp + (size_t)98304 * 8, H,
                                                    N_NODES, 512, 256, 0, flagp);
    k_agg_fuse<<<AGB, 256, 0, stream>>>(H, rowptr, csr_src, csr_norm, selfnorm,
                                        biasf + 1536, biasf + 2048, h5);

    k_final<<<NB, 256, 0, stream>>>(h5, rowptr, csr_src, csr_norm, selfnorm, b5, flagp,
                                    d_out);
}

// Round 15
// 459.055 us; speedup vs baseline: 1.0400x; 1.0400x over previous
//
#include <hip/hip_runtime.h>
#include <cstdint>
#include <cstddef>

#define N_NODES 20000
#define N_EDGES 400000
#define NBLK 79  // ceil(20000/256)
#define MPAD 20128  // N_NODES rounded up to 128-row tiles

typedef __attribute__((ext_vector_type(8))) short bf16x8;
typedef __attribute__((ext_vector_type(4))) float f32x4;

// ---------- bf16 helpers (manual, bit-exact) ----------
__device__ __forceinline__ float bf2f(unsigned short u) {
    return __uint_as_float(((unsigned int)u) << 16);
}
__device__ __forceinline__ unsigned short f2bf(float f) {
    unsigned int x = __float_as_uint(f);
    unsigned int lsb = (x >> 16) & 1u;
    x += 0x7fffu + lsb;  // round-to-nearest-even
    return (unsigned short)(x >> 16);
}

// ---------- flag-aware loads for harness float tensors (bf16 or fp32) ----------
__device__ __forceinline__ float ldF(const void* p, size_t i, bool bf) {
    return bf ? bf2f(((const unsigned short*)p)[i]) : ((const float*)p)[i];
}

// ---------- async global->LDS 16B copy ----------
__device__ __forceinline__ void gl2lds16(const unsigned short* g, unsigned short* l) {
    __builtin_amdgcn_global_load_lds(
        (const __attribute__((address_space(1))) void*)g,
        (__attribute__((address_space(3))) void*)l, 16, 0, 0);
}

// ---------- dtype + int64 detection (one wave, lane-parallel) ----------
__global__ void k_detect(const unsigned int* __restrict__ xw, const int* __restrict__ raw,
                         int* __restrict__ flag) {
    int lane = threadIdx.x;
    int cnt = 0, nz = 0;
    for (int i = lane; i < 256; i += 64) {
        unsigned short lo = (unsigned short)(xw[i] & 0xffffu);
        int e = (lo >> 7) & 0xff;
        if (e >= 110 && e <= 135) cnt++;
    }
    for (int i = 2 * lane + 1; i < 512; i += 128)
        if (raw[i] != 0) nz++;
#pragma unroll
    for (int off = 32; off > 0; off >>= 1) {
        cnt += __shfl_down(cnt, off);
        nz  += __shfl_down(nz, off);
    }
    if (lane == 0) {
        flag[0] = (cnt >= 128) ? 1 : 0;  // 1 = float tensors are bf16
        flag[1] = (nz == 0) ? 1 : 0;     // 1 = edge_index is raw int64
    }
}

// ---------- canonicalize edge_index + degree + counts (fused) ----------
__global__ void k_canon_deg(const int* __restrict__ raw, const void* __restrict__ ew,
                            const int* __restrict__ flagp,
                            int* __restrict__ src32, int* __restrict__ dst32,
                            float* __restrict__ deg, int* __restrict__ counts) {
    bool bf = (flagp[0] != 0);
    int is64 = flagp[1];
    int e = blockIdx.x * blockDim.x + threadIdx.x;
    if (e >= N_EDGES) return;
    int s, d;
    if (is64) { s = raw[2 * e]; d = raw[2 * (N_EDGES + e)]; }
    else      { s = raw[e];     d = raw[N_EDGES + e]; }
    src32[e] = s;
    dst32[e] = d;
    atomicAdd(&deg[d], ldF(ew, e, bf));
    atomicAdd(&counts[d], 1);
}

// ---------- pass 1: per-block count sums + fused dinv/selfnorm ----------
__global__ __launch_bounds__(256) void k_part(const int* __restrict__ counts,
                                              const float* __restrict__ deg,
                                              float* __restrict__ dinv,
                                              float* __restrict__ selfnorm,
                                              int* __restrict__ bsum) {
    __shared__ int s[256];
    int t = threadIdx.x;
    int i = blockIdx.x * 256 + t;
    int c = (i < N_NODES) ? counts[i] : 0;
    if (i < N_NODES) {
        float d = deg[i] + 1.0f;
        float r = rsqrtf(d);
        dinv[i] = r;
        selfnorm[i] = r * r;
    }
    s[t] = c;
    __syncthreads();
    for (int off = 128; off > 0; off >>= 1) {
        if (t < off) s[t] += s[t + off];
        __syncthreads();
    }
    if (t == 0) bsum[blockIdx.x] = s[0];
}

// ---------- pass 2: exclusive scan of 79 block sums (1 tiny block) ----------
__global__ void k_scanb(const int* __restrict__ bsum, int* __restrict__ bofs,
                        int* __restrict__ rowptr) {
    __shared__ int s[128];
    int t = threadIdx.x;
    int v = (t < NBLK) ? bsum[t] : 0;
    s[t] = v;
    __syncthreads();
    for (int off = 1; off < 128; off <<= 1) {
        int u = (t >= off) ? s[t - off] : 0;
        __syncthreads();
        s[t] += u;
        __syncthreads();
    }
    if (t < NBLK) bofs[t] = s[t] - v;  // exclusive
    if (t == NBLK - 1) rowptr[N_NODES] = s[t];
}

// ---------- pass 3: intra-block scan + block offset -> rowptr ----------
__global__ __launch_bounds__(256) void k_row(const int* __restrict__ counts,
                                             const int* __restrict__ bofs,
                                             int* __restrict__ rowptr) {
    __shared__ int s[256];
    int t = threadIdx.x;
    int b = blockIdx.x;
    int i = b * 256 + t;
    int c = (i < N_NODES) ? counts[i] : 0;
    s[t] = c;
    __syncthreads();
    for (int off = 1; off < 256; off <<= 1) {
        int u = (t >= off) ? s[t - off] : 0;
        __syncthreads();
        s[t] += u;
        __syncthreads();
    }
    if (i < N_NODES) rowptr[i] = bofs[b] + s[t] - c;
}

// ---------- scatter edges into CSR-by-dst with per-edge norm ----------
__global__ void k_csr(const int* __restrict__ src, const int* __restrict__ dst,
                      const void* __restrict__ ew, const int* __restrict__ flagp,
                      const float* __restrict__ dinv, const int* __restrict__ rowptr,
                      int* __restrict__ fill, int* __restrict__ csr_src,
                      float* __restrict__ csr_norm) {
    bool bf = (*flagp != 0);
    int e = blockIdx.x * blockDim.x + threadIdx.x;
    if (e >= N_EDGES) return;
    int s = src[e], d = dst[e];
    int p = rowptr[d] + atomicAdd(&fill[d], 1);
    csr_src[p] = s;
    csr_norm[p] = dinv[s] * ldF(ew, e, bf) * dinv[d];
}

// ---------- merged prep: cast x -> bf16 | pack weights | cast biases+W5 -> fp32 ----------
__global__ __launch_bounds__(256) void k_prep(const void* __restrict__ x,
                                              const void* __restrict__ W1,
                                              const void* __restrict__ W2,
                                              const void* __restrict__ W3,
                                              const void* __restrict__ W4,
                                              const void* __restrict__ b1,
                                              const void* __restrict__ b2,
                                              const void* __restrict__ b3,
                                              const void* __restrict__ b4,
                                              const void* __restrict__ W5,
                                              const int* __restrict__ flagp,
                                              unsigned short* __restrict__ P,
                                              unsigned short* __restrict__ Wp,
                                              float* __restrict__ biasf) {
    bool bf = (*flagp != 0);
    int b = blockIdx.x;
    int t = threadIdx.x;
    if (b < 10000) {
        int i = b * 256 + t;  // < 2,560,000 exactly
        if (bf) {
            ((uint2*)P)[i] = ((const uint2*)x)[i];
        } else {
            float4 v = ((const float4*)x)[i];
            unsigned int lo = (unsigned int)f2bf(v.x) | ((unsigned int)f2bf(v.y) << 16);
            unsigned int hi = (unsigned int)f2bf(v.z) | ((unsigned int)f2bf(v.w) << 16);
            ((uint2*)P)[i] = make_uint2(lo, hi);
        }
    } else if (b < 10448) {
        int gidx = (b - 10000) * 256 + t;
        if (gidx >= 114688) return;
        const void* W;
        int idx = gidx, N, nbl;
        if (gidx < 32768)      { W = W1; N = 512; nbl = 5; }
        else if (gidx < 65536) { W = W2; N = 512; nbl = 5; idx -= 32768; }
        else if (gidx < 98304) { W = W3; N = 512; nbl = 5; idx -= 65536; }
        else                   { W = W4; N = 256; nbl = 4; idx -= 98304; }
        int lane = idx & 63;
        int blk = idx >> 6;
        int nb = blk & ((1 << nbl) - 1);
        int kb = blk >> nbl;
        int n = (nb << 4) + (lane & 15);
        int kbase = (kb << 5) + ((lane >> 4) << 3);
        unsigned short o[8];
#pragma unroll
        for (int j = 0; j < 8; ++j)
            o[j] = f2bf(ldF(W, (size_t)(kbase + j) * N + n, bf));
        *(uint4*)(&Wp[(size_t)gidx * 8]) = *(const uint4*)o;
    } else {
        int i = (b - 10448) * 256 + t;
        if (i >= 2304) return;
        if (i < 2048) {
            int L = i >> 9, r = i & 511;
            if (L == 3 && r >= 256) return;
            const void* bb = (L == 0) ? b1 : (L == 1) ? b2 : (L == 2) ? b3 : b4;
            biasf[i] = ldF(bb, r, bf);
        } else {
            biasf[i] = ldF(W5, i - 2048, bf);  // fp32 W5 at biasf[2048..2303]
        }
    }
}

// ---------- MFMA bf16 GEMM, 128x128 tile, BK=64: C = A * Wp(packed) ----------
// 256 threads / 4 waves in 2x2; wave tile 64x64 (4x4 MFMA 16x16x32).
// BK=64: 8 K-iterations, 32 MFMA per barrier (2x the amortization of BK=32).
__global__ __launch_bounds__(256) void k_gemm_mfma(const unsigned short* __restrict__ A,
                                                   const unsigned short* __restrict__ Bp,
                                                   unsigned short* __restrict__ C,
                                                   int M, int K, int N) {
    const int AP = 72;  // A-tile row stride (64 + 8 pad) shorts -> 2-way-max banks
    __shared__ __align__(16) unsigned short As[128 * AP];  // 18432 B
    __shared__ __align__(16) unsigned short Bs[2 * 8 * 512];  // 16384 B
    int tid = threadIdx.x;
    int lane = tid & 63;
    int wave = tid >> 6;
    int wr = wave >> 1, wc = wave & 1;
    int row0 = blockIdx.x * 128;
    int col0 = blockIdx.y * 128;
    int nbt = N >> 4;
    int q = lane >> 4;
    int mm = lane & 15;

    f32x4 acc[4][4] = {};

    for (int kb2 = 0; kb2 < (K >> 6); ++kb2) {
        // B: two packed kb-regions (k 0-31 and 32-63 of this BK), 8 KB each
        const unsigned short* breg0 = Bp + (((size_t)(2 * kb2) * nbt + (col0 >> 4)) << 9);
        const unsigned short* breg1 = Bp + (((size_t)(2 * kb2 + 1) * nbt + (col0 >> 4)) << 9);
        gl2lds16(breg0 + (size_t)tid * 8, &Bs[(size_t)tid * 8]);
        gl2lds16(breg0 + (size_t)(tid + 256) * 8, &Bs[(size_t)(tid + 256) * 8]);
        gl2lds16(breg1 + (size_t)tid * 8, &Bs[4096 + (size_t)tid * 8]);
        gl2lds16(breg1 + (size_t)(tid + 256) * 8, &Bs[4096 + (size_t)(tid + 256) * 8]);
        // A tile: 128 rows x 64 k (16KB), 1024 x 16B chunks, 4 per thread
#pragma unroll
        for (int i = 0; i < 4; ++i) {
            int c = tid + i * 256;
            int row = c >> 3, kq = c & 7;
            uint4 v = *(const uint4*)(&A[(size_t)(row0 + row) * K + (kb2 << 6) + (kq << 3)]);
            *(uint4*)(&As[row * AP + (kq << 3)]) = v;
        }
        __syncthreads();
#pragma unroll
        for (int kk = 0; kk < 2; ++kk) {
            bf16x8 af[4], bfr[4];
#pragma unroll
            for (int mb = 0; mb < 4; ++mb)
                af[mb] = *(const bf16x8*)(&As[(wr * 64 + mb * 16 + mm) * AP + kk * 32 + q * 8]);
#pragma unroll
            for (int nb = 0; nb < 4; ++nb)
                bfr[nb] = *(const bf16x8*)(&Bs[kk * 4096 + ((wc * 4 + nb) * 64 + lane) * 8]);
#pragma unroll
            for (int mb = 0; mb < 4; ++mb)
#pragma unroll
                for (int nb = 0; nb < 4; ++nb)
                    acc[mb][nb] = __builtin_amdgcn_mfma_f32_16x16x32_bf16(
                        af[mb], bfr[nb], acc[mb][nb], 0, 0, 0);
        }
        __syncthreads();
    }
#pragma unroll
    for (int mb = 0; mb < 4; ++mb) {
#pragma unroll
        for (int r = 0; r < 4; ++r) {
            int grow = row0 + wr * 64 + mb * 16 + q * 4 + r;
            if (grow < M) {
#pragma unroll
                for (int nb = 0; nb < 4; ++nb) {
                    int gcol = col0 + wc * 64 + nb * 16 + mm;
                    C[(size_t)grow * N + gcol] = f2bf(acc[mb][nb][r]);
                }
            }
        }
    }
}

// ---------- row-load + fma helpers for the gather ----------
template <int W>
__device__ __forceinline__ void ldrow(const unsigned short* h, size_t row, int F, int lane,
                                      unsigned int* u) {
    const unsigned int* p = (const unsigned int*)(h + row * F) + lane * W;
    if constexpr (W == 4) {
        uint4 v = *(const uint4*)p; u[0] = v.x; u[1] = v.y; u[2] = v.z; u[3] = v.w;
    } else {
        uint2 v = *(const uint2*)p; u[0] = v.x; u[1] = v.y;
    }
}
template <int W>
__device__ __forceinline__ void fmarow(const unsigned int* u, float w, float* acc) {
#pragma unroll
    for (int k = 0; k < W; ++k) {
        acc[2 * k]     = fmaf(bf2f((unsigned short)(u[k] & 0xffffu)), w, acc[2 * k]);
        acc[2 * k + 1] = fmaf(bf2f((unsigned short)(u[k] >> 16)),     w, acc[2 * k + 1]);
    }
}

// ---------- wave-per-node gather-aggregate, 4-edge unroll (F=512) ----------
__global__ __launch_bounds__(256) void k_agg_w(const unsigned short* __restrict__ h,
                                               const int* __restrict__ rowptr,
                                               const int* __restrict__ csr_src,
                                               const float* __restrict__ csr_norm,
                                               const float* __restrict__ selfnorm,
                                               const float* __restrict__ biasf,
                                               unsigned short* __restrict__ out) {
    constexpr int F = 512, FPL = 8, W = 4;
    int lane = threadIdx.x & 63;
    int wave = threadIdx.x >> 6;
    int node = blockIdx.x * 4 + wave;
    if (node >= N_NODES) return;
    int e0 = rowptr[node], e1 = rowptr[node + 1];
    float sn = selfnorm[node];

    float acc[FPL];
    {
        unsigned int u[W];
        ldrow<W>(h, (size_t)node, F, lane, u);
#pragma unroll
        for (int k = 0; k < W; ++k) {
            acc[2 * k]     = sn * bf2f((unsigned short)(u[k] & 0xffffu));
            acc[2 * k + 1] = sn * bf2f((unsigned short)(u[k] >> 16));
        }
    }
    int j = e0;
    for (; j + 3 < e1; j += 4) {
        int s0 = csr_src[j], s1 = csr_src[j + 1], s2 = csr_src[j + 2], s3 = csr_src[j + 3];
        float w0 = csr_norm[j], w1 = csr_norm[j + 1], w2 = csr_norm[j + 2], w3 = csr_norm[j + 3];
        unsigned int u0[W], u1[W], u2[W], u3[W];
        ldrow<W>(h, (size_t)s0, F, lane, u0);
        ldrow<W>(h, (size_t)s1, F, lane, u1);
        ldrow<W>(h, (size_t)s2, F, lane, u2);
        ldrow<W>(h, (size_t)s3, F, lane, u3);
        fmarow<W>(u0, w0, acc);
        fmarow<W>(u1, w1, acc);
        fmarow<W>(u2, w2, acc);
        fmarow<W>(u3, w3, acc);
    }
    for (; j < e1; ++j) {
        int s0 = csr_src[j];
        float w0 = csr_norm[j];
        unsigned int u0[W];
        ldrow<W>(h, (size_t)s0, F, lane, u0);
        fmarow<W>(u0, w0, acc);
    }
    {
        const float* bp = biasf + lane * FPL;
#pragma unroll
        for (int k = 0; k < FPL; ++k) acc[k] = fmaxf(acc[k] + bp[k], 0.f);
        unsigned int o[W];
#pragma unroll
        for (int k = 0; k < W; ++k)
            o[k] = (unsigned int)f2bf(acc[2 * k]) | ((unsigned int)f2bf(acc[2 * k + 1]) << 16);
        *(uint4*)((unsigned int*)(out + (size_t)node * F) + lane * W) =
            make_uint4(o[0], o[1], o[2], o[3]);
    }
}

// ---------- L4 agg fused with L5 GEMV: h5[node] = dot(relu(agg+b4), W5) ----------
__global__ __launch_bounds__(256) void k_agg_fuse(const unsigned short* __restrict__ h,
                                                  const int* __restrict__ rowptr,
                                                  const int* __restrict__ csr_src,
                                                  const float* __restrict__ csr_norm,
                                                  const float* __restrict__ selfnorm,
                                                  const float* __restrict__ biasf,
                                                  const float* __restrict__ w5f,
                                                  float* __restrict__ h5) {
    constexpr int F = 256, FPL = 4, W = 2;
    int lane = threadIdx.x & 63;
    int wave = threadIdx.x >> 6;
    int node = blockIdx.x * 4 + wave;
    if (node >= N_NODES) return;
    int e0 = rowptr[node], e1 = rowptr[node + 1];
    float sn = selfnorm[node];

    float acc[FPL];
    {
        unsigned int u[W];
        ldrow<W>(h, (size_t)node, F, lane, u);
#pragma unroll
        for (int k = 0; k < W; ++k) {
            acc[2 * k]     = sn * bf2f((unsigned short)(u[k] & 0xffffu));
            acc[2 * k + 1] = sn * bf2f((unsigned short)(u[k] >> 16));
        }
    }
    int j = e0;
    for (; j + 3 < e1; j += 4) {
        int s0 = csr_src[j], s1 = csr_src[j + 1], s2 = csr_src[j + 2], s3 = csr_src[j + 3];
        float w0 = csr_norm[j], w1 = csr_norm[j + 1], w2 = csr_norm[j + 2], w3 = csr_norm[j + 3];
        unsigned int u0[W], u1[W], u2[W], u3[W];
        ldrow<W>(h, (size_t)s0, F, lane, u0);
        ldrow<W>(h, (size_t)s1, F, lane, u1);
        ldrow<W>(h, (size_t)s2, F, lane, u2);
        ldrow<W>(h, (size_t)s3, F, lane, u3);
        fmarow<W>(u0, w0, acc);
        fmarow<W>(u1, w1, acc);
        fmarow<W>(u2, w2, acc);
        fmarow<W>(u3, w3, acc);
    }
    for (; j < e1; ++j) {
        int s0 = csr_src[j];
        float w0 = csr_norm[j];
        unsigned int u0[W];
        ldrow<W>(h, (size_t)s0, F, lane, u0);
        fmarow<W>(u0, w0, acc);
    }
    const float* bp = biasf + lane * FPL;
    const float* wp = w5f + lane * FPL;
    float partial = 0.f;
#pragma unroll
    for (int k = 0; k < FPL; ++k)
        partial += fmaxf(acc[k] + bp[k], 0.f) * wp[k];
#pragma unroll
    for (int off = 32; off > 0; off >>= 1)
        partial += __shfl_xor(partial, off);
    if (lane == 0) h5[node] = partial;
}

// ---------- final scalar aggregate, write output in harness dtype ----------
__global__ void k_final(const float* __restrict__ h5, const int* __restrict__ rowptr,
                        const int* __restrict__ csr_src, const float* __restrict__ csr_norm,
                        const float* __restrict__ selfnorm,
                        const void* __restrict__ b5, const int* __restrict__ flagp,
                        void* __restrict__ out) {
    bool bf = (*flagp != 0);
    int i = blockIdx.x * blockDim.x + threadIdx.x;
    if (i >= N_NODES) return;
    float acc = selfnorm[i] * h5[i];
    int e0 = rowptr[i], e1 = rowptr[i + 1];
    for (int j = e0; j < e1; ++j) acc += csr_norm[j] * h5[csr_src[j]];
    acc += ldF(b5, 0, bf);
    if (bf) ((unsigned short*)out)[i] = f2bf(acc);
    else    ((float*)out)[i] = acc;
}

extern "C" void kernel_launch(void* const* d_in, const int* in_sizes, int n_in,
                              void* d_out, int out_size, void* d_ws, size_t ws_size,
                              hipStream_t stream) {
    const void* x  = d_in[0];
    const int*  ei = (const int*)d_in[1];
    const void* ea = d_in[2];
    const void* W1 = d_in[3];
    const void* b1 = d_in[4];
    const void* W2 = d_in[5];
    const void* b2 = d_in[6];
    const void* W3 = d_in[7];
    const void* b3 = d_in[8];
    const void* W4 = d_in[9];
    const void* b4 = d_in[10];
    const void* W5 = d_in[11];
    const void* b5 = d_in[12];

    char* ws = (char*)d_ws;
    size_t off = 0;
    auto take = [&](size_t bytes) -> void* {
        off = (off + 255) & ~(size_t)255;
        void* p = ws + off;
        off += bytes;
        return p;
    };
    int*   flagp    = (int*)take(2 * sizeof(int));
    float* deg      = (float*)take(N_NODES * sizeof(float));
    int*   counts   = (int*)take(N_NODES * sizeof(int));
    int*   fill     = (int*)take(N_NODES * sizeof(int));
    size_t zspan    = (size_t)((char*)(fill + N_NODES) - (char*)deg);
    float* dinv     = (float*)take(N_NODES * sizeof(float));
    float* selfnorm = (float*)take(N_NODES * sizeof(float));
    float* h5       = (float*)take(N_NODES * sizeof(float));
    float* biasf    = (float*)take(2304 * sizeof(float));  // 4x512 biases + 256 W5
    int*   bsum     = (int*)take(128 * sizeof(int));
    int*   bofs     = (int*)take(128 * sizeof(int));
    int*   rowptr   = (int*)take((N_NODES + 1) * sizeof(int));
    int*   src32    = (int*)take(N_EDGES * sizeof(int));
    int*   dst32    = (int*)take(N_EDGES * sizeof(int));
    int*   csr_src  = (int*)take(N_EDGES * sizeof(int));
    float* csr_norm = (float*)take(N_EDGES * sizeof(float));
    unsigned short* Wp = (unsigned short*)take((size_t)114688 * 8 * sizeof(unsigned short));
    unsigned short* P  = (unsigned short*)take((size_t)MPAD * 512 * sizeof(unsigned short));
    unsigned short* H  = (unsigned short*)take((size_t)MPAD * 512 * sizeof(unsigned short));

    hipMemsetAsync(deg, 0, zspan, stream);

    const int EB = (N_EDGES + 255) / 256;
    const int NB = (N_NODES + 255) / 256;  // 79 == NBLK
    const int AGB = (N_NODES + 3) / 4;

    k_detect<<<1, 64, 0, stream>>>((const unsigned int*)x, ei, flagp);
    k_canon_deg<<<EB, 256, 0, stream>>>(ei, ea, flagp, src32, dst32, deg, counts);
    k_part<<<NB, 256, 0, stream>>>(counts, deg, dinv, selfnorm, bsum);
    k_scanb<<<1, 128, 0, stream>>>(bsum, bofs, rowptr);
    k_row<<<NB, 256, 0, stream>>>(counts, bofs, rowptr);
    k_csr<<<EB, 256, 0, stream>>>(src32, dst32, ea, flagp, dinv, rowptr, fill, csr_src, csr_norm);

    k_prep<<<10457, 256, 0, stream>>>(x, W1, W2, W3, W4, b1, b2, b3, b4, W5, flagp,
                                      P, Wp, biasf);

    const int MB128 = (N_NODES + 127) / 128;  // 157

    k_gemm_mfma<<<dim3(MB128, 4), 256, 0, stream>>>(P, Wp, H, N_NODES, 512, 512);
    k_agg_w<<<AGB, 256, 0, stream>>>(H, rowptr, csr_src, csr_norm, selfnorm, biasf, P);
    k_gemm_mfma<<<dim3(MB128, 4), 256, 0, stream>>>(P, Wp + (size_t)32768 * 8, H,
                                                    N_NODES, 512, 512);
    k_agg_w<<<AGB, 256, 0, stream>>>(H, rowptr, csr_src, csr_norm, selfnorm, biasf + 512, P);
    k_gemm_mfma<<<dim3(MB128, 4), 256, 0, stream>>>(P, Wp + (size_t)65536 * 8, H,
                                                    N_NODES, 512, 512);
    k_agg_w<<<AGB, 256, 0, stream>>>(H, rowptr, csr_src, csr_norm, selfnorm, biasf + 1024, P);
    k_gemm_mfma<<<dim3(MB128, 2), 256, 0, stream>>>(P, Wp + (size_t)98304 * 8, H,
                                                    N_NODES, 512, 256);
    k_agg_fuse<<<AGB, 256, 0, stream>>>(H, rowptr, csr_src, csr_norm, selfnorm,
                                        biasf + 1536, biasf + 2048, h5);

    k_final<<<NB, 256, 0, stream>>>(h5, rowptr, csr_src, csr_norm, selfnorm, b5, flagp,
                                    d_out);
}